// Round 3
// baseline (26.113 us; speedup 1.0000x reference)
//
#include <hip/hip_runtime.h>
#include <math.h>

// CAM_Module: out = alpha * attention(x) + x, with x:[B=8,H=64,W=64,C=512] f32,
// alpha:[1] f32 (== 0 for the bench inputs).
//
// Fast path (alpha == 0): reference output is exactly x -> vectorized copy.
//   R1/R2 tuning: exact-fit grid (4 float4/thread), 4x batched independent
//   loads (ILP), non-temporal stores via clang ext_vector_type (HIP float4 is
//   a class and is rejected by __builtin_nontemporal_store).
// General path (alpha != 0): flash-style online softmax of (-energy) per row,
//   out[b,n,:] = alpha * (sum_m p_m q[m,:]) / (sum_m p_m) + x[b,n,:],
//   p_m = exp(min_e - e_m), e_m = dot(q[n], q[m]).
// Both paths are pure functions of the inputs -> deterministic.

#define BLOCK 256

typedef __attribute__((ext_vector_type(4))) float f32x4;

__global__ __launch_bounds__(BLOCK) void cam_module_kernel(
    const float* __restrict__ x, const float* __restrict__ alpha,
    float* __restrict__ out, int n4, int B, int N, int C)
{
    const float a = alpha[0];

    if (a == 0.0f) {
        // ---- fast path: out = x (exact) ----
        const f32x4* __restrict__ xv = reinterpret_cast<const f32x4*>(x);
        f32x4* __restrict__ ov = reinterpret_cast<f32x4*>(out);
        const int stride = gridDim.x * blockDim.x;
        int i = blockIdx.x * blockDim.x + threadIdx.x;
        // main: 4 independent loads in flight, then 4 nt stores
        for (; i + 3 * stride < n4; i += 4 * stride) {
            const f32x4 v0 = xv[i];
            const f32x4 v1 = xv[i + stride];
            const f32x4 v2 = xv[i + 2 * stride];
            const f32x4 v3 = xv[i + 3 * stride];
            __builtin_nontemporal_store(v0, &ov[i]);
            __builtin_nontemporal_store(v1, &ov[i + stride]);
            __builtin_nontemporal_store(v2, &ov[i + 2 * stride]);
            __builtin_nontemporal_store(v3, &ov[i + 3 * stride]);
        }
        for (; i < n4; i += stride)
            __builtin_nontemporal_store(xv[i], &ov[i]);
        return;
    }

    // ---- general path (dead for bench inputs, kept correct) ----
    const int lane   = threadIdx.x & 63;
    const int wave   = threadIdx.x >> 6;          // 4 waves / block
    const int nwaves = BLOCK / 64;
    const int CPL    = C / 64;                    // 8 channels per lane

    __shared__ float s_acc[512];
    __shared__ float s_min[4];
    __shared__ float s_tot;

    const long long rows_total = (long long)B * N;
    for (long long row = blockIdx.x; row < rows_total; row += gridDim.x) {
        const int b = (int)(row / N);
        const int n = (int)(row % N);
        const float* __restrict__ qb = x + (long long)b * N * C;
        const float* __restrict__ qn = qb + (long long)n * C;

        float qf[8];
        #pragma unroll
        for (int j = 0; j < 8; ++j) qf[j] = qn[lane * CPL + j];

        float mn   = INFINITY;   // running min of energy e_m
        float ssum = 0.0f;
        float acc[8];
        #pragma unroll
        for (int j = 0; j < 8; ++j) acc[j] = 0.0f;

        for (int m = wave; m < N; m += nwaves) {
            const float* __restrict__ qm = qb + (long long)m * C;
            float qmf[8];
            float e = 0.0f;
            #pragma unroll
            for (int j = 0; j < 8; ++j) {
                qmf[j] = qm[lane * CPL + j];
                e += qf[j] * qmf[j];
            }
            #pragma unroll
            for (int off = 32; off > 0; off >>= 1) e += __shfl_xor(e, off, 64);

            const float mn_new = fminf(mn, e);
            if (mn_new < mn) {
                const float sc = expf(mn_new - mn);
                ssum *= sc;
                #pragma unroll
                for (int j = 0; j < 8; ++j) acc[j] *= sc;
                mn = mn_new;
            }
            const float p = expf(mn - e);
            ssum += p;
            #pragma unroll
            for (int j = 0; j < 8; ++j) acc[j] += p * qmf[j];
        }

        // combine the 4 waves' partial (min, sum, acc)
        if (lane == 0) s_min[wave] = mn;
        for (int c = threadIdx.x; c < C; c += BLOCK) s_acc[c] = 0.0f;
        if (threadIdx.x == 0) s_tot = 0.0f;
        __syncthreads();

        const float gmn = fminf(fminf(s_min[0], s_min[1]),
                                fminf(s_min[2], s_min[3]));
        const float sc = expf(gmn - mn);   // exp(-inf)=0 handles empty waves
        #pragma unroll
        for (int j = 0; j < 8; ++j)
            atomicAdd(&s_acc[lane * CPL + j], acc[j] * sc);
        if (lane == 0) atomicAdd(&s_tot, ssum * sc);
        __syncthreads();

        const float inv = 1.0f / s_tot;
        float* __restrict__ on = out + (long long)b * N * C + (long long)n * C;
        for (int c = threadIdx.x; c < C; c += BLOCK)
            on[c] = a * (s_acc[c] * inv) + qn[c];
        __syncthreads();   // protect s_* before next row
    }
}

extern "C" void kernel_launch(void* const* d_in, const int* in_sizes, int n_in,
                              void* d_out, int out_size, void* d_ws, size_t ws_size,
                              hipStream_t stream) {
    (void)d_ws; (void)ws_size; (void)n_in; (void)in_sizes;
    const float* x     = (const float*)d_in[0];
    const float* alpha = (const float*)d_in[1];
    float* out         = (float*)d_out;

    const int B = 8, H = 64, W = 64, C = 512;
    const int N = H * W;
    const int n4 = out_size / 4;   // float4 count (4,194,304)

    // exact fit for the copy path: 4096 blk x 256 thr = 1Mi threads x 4 float4
    const int blocks = 4096;
    cam_module_kernel<<<blocks, BLOCK, 0, stream>>>(x, alpha, out, n4, B, N, C);
}

// Round 4
// 25.891 us; speedup vs baseline: 1.0086x; 1.0086x over previous
//
#include <hip/hip_runtime.h>
#include <math.h>

// CAM_Module: out = alpha * attention(x) + x, with x:[B=8,H=64,W=64,C=512] f32,
// alpha:[1] f32 (== 0 for the bench inputs).
//
// R4 structure:
//   1) hipMemcpyAsync(out <- x, 64 MB, D2D) unconditionally — the reference
//      output is exactly x when alpha == 0, and the runtime blit is the
//      best-tuned copy machinery on this chip (fills sustain 6.4-6.7 TB/s).
//   2) guard kernel: reads alpha; if alpha != 0 overwrites out with the full
//      flash-style general path (online softmax of -energy per row):
//        out[b,n,:] = alpha * (sum_m p_m q[m,:]) / (sum_m p_m) + x[b,n,:]
//      If alpha == 0 it exits immediately (~2-4 us, uniform branch).
// memcpy-first ordering keeps both alpha cases correct; everything is a pure
// function of the inputs -> deterministic under graph replay.

#define BLOCK 256

__global__ __launch_bounds__(BLOCK) void cam_guard_kernel(
    const float* __restrict__ x, const float* __restrict__ alpha,
    float* __restrict__ out, int B, int N, int C)
{
    const float a = alpha[0];
    if (a == 0.0f) return;   // out already == x from the blit

    // ---- general path (dead for bench inputs, kept correct) ----
    const int lane   = threadIdx.x & 63;
    const int wave   = threadIdx.x >> 6;          // 4 waves / block
    const int nwaves = BLOCK / 64;
    const int CPL    = C / 64;                    // 8 channels per lane

    __shared__ float s_acc[512];
    __shared__ float s_min[4];
    __shared__ float s_tot;

    const long long rows_total = (long long)B * N;
    for (long long row = blockIdx.x; row < rows_total; row += gridDim.x) {
        const int b = (int)(row / N);
        const int n = (int)(row % N);
        const float* __restrict__ qb = x + (long long)b * N * C;
        const float* __restrict__ qn = qb + (long long)n * C;

        float qf[8];
        #pragma unroll
        for (int j = 0; j < 8; ++j) qf[j] = qn[lane * CPL + j];

        float mn   = INFINITY;   // running min of energy e_m
        float ssum = 0.0f;
        float acc[8];
        #pragma unroll
        for (int j = 0; j < 8; ++j) acc[j] = 0.0f;

        for (int m = wave; m < N; m += nwaves) {
            const float* __restrict__ qm = qb + (long long)m * C;
            float qmf[8];
            float e = 0.0f;
            #pragma unroll
            for (int j = 0; j < 8; ++j) {
                qmf[j] = qm[lane * CPL + j];
                e += qf[j] * qmf[j];
            }
            #pragma unroll
            for (int off = 32; off > 0; off >>= 1) e += __shfl_xor(e, off, 64);

            const float mn_new = fminf(mn, e);
            if (mn_new < mn) {
                const float sc = expf(mn_new - mn);
                ssum *= sc;
                #pragma unroll
                for (int j = 0; j < 8; ++j) acc[j] *= sc;
                mn = mn_new;
            }
            const float p = expf(mn - e);
            ssum += p;
            #pragma unroll
            for (int j = 0; j < 8; ++j) acc[j] += p * qmf[j];
        }

        // combine the 4 waves' partial (min, sum, acc)
        if (lane == 0) s_min[wave] = mn;
        for (int c = threadIdx.x; c < C; c += BLOCK) s_acc[c] = 0.0f;
        if (threadIdx.x == 0) s_tot = 0.0f;
        __syncthreads();

        const float gmn = fminf(fminf(s_min[0], s_min[1]),
                                fminf(s_min[2], s_min[3]));
        const float sc = expf(gmn - mn);   // exp(-inf)=0 handles empty waves
        #pragma unroll
        for (int j = 0; j < 8; ++j)
            atomicAdd(&s_acc[lane * CPL + j], acc[j] * sc);
        if (lane == 0) atomicAdd(&s_tot, ssum * sc);
        __syncthreads();

        const float inv = 1.0f / s_tot;
        float* __restrict__ on = out + (long long)b * N * C + (long long)n * C;
        for (int c = threadIdx.x; c < BLOCK ? 0 : 0, c < C; c += BLOCK)
            on[c] = a * (s_acc[c] * inv) + qn[c];
        __syncthreads();   // protect s_* before next row
    }
}

extern "C" void kernel_launch(void* const* d_in, const int* in_sizes, int n_in,
                              void* d_out, int out_size, void* d_ws, size_t ws_size,
                              hipStream_t stream) {
    (void)d_ws; (void)ws_size; (void)n_in; (void)in_sizes;
    const float* x     = (const float*)d_in[0];
    const float* alpha = (const float*)d_in[1];
    float* out         = (float*)d_out;

    const int B = 8, H = 64, W = 64, C = 512;
    const int N = H * W;

    // 1) out = x via the runtime's tuned D2D blit (graph-capture legal).
    const size_t bytes = (size_t)out_size * sizeof(float);   // 64 MiB
    hipMemcpyAsync(out, x, bytes, hipMemcpyDeviceToDevice, stream);

    // 2) alpha-conditional general path (no-op when alpha == 0).
    cam_guard_kernel<<<2048, BLOCK, 0, stream>>>(x, alpha, out, B, N, C);
}